// Round 3
// baseline (557.898 us; speedup 1.0000x reference)
//
#include <hip/hip_runtime.h>
#include <hip/hip_bf16.h>

#define NN 50000
#define NE 400000
#define SCAN_NB 196   // ceil(50000/256)

__global__ void k_zero(int* __restrict__ cnt){
  int i = blockIdx.x*256 + threadIdx.x;
  if (i < NN) cnt[i] = 0;
}

__global__ void k_hist(const int* __restrict__ rcv, int* __restrict__ cnt){
  int e = blockIdx.x*256 + threadIdx.x;
  if (e < NE) atomicAdd(&cnt[rcv[e]], 1);
}

__global__ void k_scanA(const int* __restrict__ cnt, int* __restrict__ bsum){
  __shared__ int sh[256];
  int i = blockIdx.x*256 + threadIdx.x;
  int v = (i < NN) ? cnt[i] : 0;
  sh[threadIdx.x] = v; __syncthreads();
  for (int off=128; off>0; off>>=1){
    if (threadIdx.x < off) sh[threadIdx.x] += sh[threadIdx.x+off];
    __syncthreads();
  }
  if (threadIdx.x==0) bsum[blockIdx.x] = sh[0];
}

__global__ void k_scanB(int* __restrict__ bsum){
  __shared__ int sh[256];
  int t = threadIdx.x;
  int v = (t < SCAN_NB) ? bsum[t] : 0;
  sh[t] = v; __syncthreads();
  for (int off=1; off<256; off<<=1){
    int x = (t>=off)? sh[t-off] : 0;
    __syncthreads();
    sh[t] += x;
    __syncthreads();
  }
  if (t < SCAN_NB) bsum[t] = sh[t] - v;   // exclusive
}

__global__ void k_scanC(const int* __restrict__ cnt, const int* __restrict__ bsum,
                        int* __restrict__ offs, int* __restrict__ cursor){
  __shared__ int sh[256];
  int t = threadIdx.x;
  int i = blockIdx.x*256 + t;
  int v = (i < NN) ? cnt[i] : 0;
  sh[t] = v; __syncthreads();
  for (int off=1; off<256; off<<=1){
    int x = (t>=off)? sh[t-off] : 0;
    __syncthreads();
    sh[t] += x;
    __syncthreads();
  }
  int excl = sh[t] - v + bsum[blockIdx.x];
  if (i < NN){ offs[i] = excl; cursor[i] = excl; }
}

__global__ void k_scatter(const int* __restrict__ rcv, int* __restrict__ cursor,
                          int* __restrict__ eord){
  int e = blockIdx.x*256 + threadIdx.x;
  if (e < NE){
    int p = atomicAdd(&cursor[rcv[e]], 1);
    eord[p] = e;
  }
}

// One wave per node, 4 waves/block, 4 nodes per wave (rep loop).
// Aggregation: lane = (m = lane&31, jh = lane>>5) owns agg[m][jh*8 .. jh*8+7] in regs.
// Matmul: lane = t (0..63); agg reads are wave-broadcast, W reads stride-1.
__global__ __launch_bounds__(256) void k_fused(
    const float* __restrict__ pos, const float* __restrict__ feat,
    const float* __restrict__ W0, const float* __restrict__ W1,
    const float* __restrict__ W2, const float* __restrict__ W3,
    const float* __restrict__ Wsc, const int* __restrict__ senders,
    const int* __restrict__ offs, const int* __restrict__ cnt,
    const int* __restrict__ eord, float* __restrict__ out)
{
  __shared__ __align__(16) float Wl[5][2048];   // W0..W3,Wsc
  __shared__ __align__(16) float agg[4][512];   // per-wave [m][j], j=0..15
  __shared__ float nfs[4][32];                  // per-wave self features

  const int tid = threadIdx.x;
  {
    const float* src[5] = {W0,W1,W2,W3,Wsc};
    #pragma unroll
    for (int w=0; w<5; ++w)
      for (int i=tid; i<2048; i+=256)
        Wl[w][i] = src[w][i];
  }
  __syncthreads();

  const int wv = tid>>6, lane = tid&63;
  const int m = lane&31, jh = lane>>5;
  const float SC3=1.7320508f, SC5=2.236068f, SC7=2.6457513f, SC15=3.8729833f,
              SC42=6.4807407f, SC70=8.3666003f, SC105=10.246951f;

  for (int rep=0; rep<4; ++rep){
    const int n = blockIdx.x*16 + rep*4 + wv;   // 3125*16 == 50000 exactly
    const float pnx=pos[n*3], pny=pos[n*3+1], pnz=pos[n*3+2];
    if (lane<32) nfs[wv][lane] = feat[n*32+lane];

    float a0=0,a1=0,a2=0,a3=0,a4=0,a5=0,a6=0,a7=0;
    const int start = offs[n], deg = cnt[n];
    for (int it=0; it<deg; ++it){
      int e = eord[start+it];
      int s = senders[e];
      float rx = pnx - pos[s*3];
      float ry = pny - pos[s*3+1];
      float rz = pnz - pos[s*3+2];
      float sfv = feat[s*32+m];
      float r = sqrtf(rx*rx+ry*ry+rz*rz);
      float inv = 1.0f/fmaxf(r,1e-12f);
      float x=rx*inv, y=ry*inv, z=rz*inv;
      float x2=x*x, y2=y*y, z2=z*z;
      float s0=1.0f, s1=SC3*x, s2=SC3*y, s3=SC3*z;
      float s4=SC15*x*y, s5=SC15*y*z, s6=0.5f*SC5*(3.f*z2-1.f), s7=SC15*x*z;
      float s8=0.5f*SC15*(x2-y2);
      float s9 =0.25f*SC70*y*(3.f*x2-y2);
      float s10=SC105*x*y*z;
      float s11=0.25f*SC42*y*(5.f*z2-1.f);
      float s12=0.5f*SC7*z*(5.f*z2-3.f);
      float s13=0.25f*SC42*x*(5.f*z2-1.f);
      float s14=0.5f*SC105*z*(x2-y2);
      float s15=0.25f*SC70*x*(x2-3.f*y2);
      a0 += sfv*(jh? s8 : s0);
      a1 += sfv*(jh? s9 : s1);
      a2 += sfv*(jh? s10: s2);
      a3 += sfv*(jh? s11: s3);
      a4 += sfv*(jh? s12: s4);
      a5 += sfv*(jh? s13: s5);
      a6 += sfv*(jh? s14: s6);
      a7 += sfv*(jh? s15: s7);
    }
    float4* ap = (float4*)&agg[wv][m*16 + jh*8];
    ap[0] = make_float4(a0,a1,a2,a3);
    ap[1] = make_float4(a4,a5,a6,a7);
    __syncthreads();   // agg + nfs visible

    float c[16];
    #pragma unroll
    for (int k=0;k<16;++k) c[k]=0.f;
    float csc = 0.f;
    #pragma unroll 8
    for (int mm=0; mm<32; ++mm){
      const float4* rp = (const float4*)&agg[wv][mm*16];
      float4 q0=rp[0], q1=rp[1], q2=rp[2], q3=rp[3];
      float w0=Wl[0][mm*64+lane], w1=Wl[1][mm*64+lane], w2=Wl[2][mm*64+lane],
            w3=Wl[3][mm*64+lane], wsc=Wl[4][mm*64+lane];
      float nfm = nfs[wv][mm];
      c[0] += q0.x*w0;
      c[1] += q0.y*w1; c[2] += q0.z*w1; c[3] += q0.w*w1;
      c[4] += q1.x*w2; c[5] += q1.y*w2; c[6] += q1.z*w2; c[7] += q1.w*w2; c[8] += q2.x*w2;
      c[9] += q2.y*w3; c[10]+= q2.z*w3; c[11]+= q2.w*w3;
      c[12]+= q3.x*w3; c[13]+= q3.y*w3; c[14]+= q3.z*w3; c[15]+= q3.w*w3;
      csc  += nfm*wsc;
    }
    const float S   = 0.17677669529663687f;  // 1/sqrt(32)
    const float S8v = S*0.125f;              // edge terms also carry /DENOM
    float* o = out + (size_t)n*1024;
    o[lane] = c[0]*S8v + csc*S;
    #pragma unroll
    for (int i=0;i<3;++i) o[64  + lane*3 + i] = c[1+i]*S8v;
    #pragma unroll
    for (int i=0;i<5;++i) o[256 + lane*5 + i] = c[4+i]*S8v;
    #pragma unroll
    for (int i=0;i<7;++i) o[576 + lane*7 + i] = c[9+i]*S8v;
    __syncthreads();   // protect agg/nfs overwrite next rep
  }
}

extern "C" void kernel_launch(void* const* d_in, const int* in_sizes, int n_in,
                              void* d_out, int out_size, void* d_ws, size_t ws_size,
                              hipStream_t stream) {
  const float* pos  = (const float*)d_in[0];
  const float* feat = (const float*)d_in[1];
  const float* W0   = (const float*)d_in[2];
  const float* W1   = (const float*)d_in[3];
  const float* W2   = (const float*)d_in[4];
  const float* W3   = (const float*)d_in[5];
  const float* Wsc  = (const float*)d_in[6];
  const int*  snd  = (const int*)d_in[7];
  const int*  rcv  = (const int*)d_in[8];
  float* out = (float*)d_out;

  int* ws     = (int*)d_ws;
  int* cnt    = ws;            // 50000
  int* offs   = ws + 50000;    // 50000
  int* cursor = ws + 100000;   // 50000
  int* bsum   = ws + 150000;   // 256
  int* eord   = ws + 150272;   // 400000

  k_zero   <<<SCAN_NB, 256, 0, stream>>>(cnt);
  k_hist   <<<(NE+255)/256, 256, 0, stream>>>(rcv, cnt);
  k_scanA  <<<SCAN_NB, 256, 0, stream>>>(cnt, bsum);
  k_scanB  <<<1, 256, 0, stream>>>(bsum);
  k_scanC  <<<SCAN_NB, 256, 0, stream>>>(cnt, bsum, offs, cursor);
  k_scatter<<<(NE+255)/256, 256, 0, stream>>>(rcv, cursor, eord);
  k_fused  <<<3125, 256, 0, stream>>>(pos, feat, W0, W1, W2, W3, Wsc,
                                      snd, offs, cnt, eord, out);
}

// Round 4
// 392.251 us; speedup vs baseline: 1.4223x; 1.4223x over previous
//
#include <hip/hip_runtime.h>

#define NN 50000
#define NE 400000
#define SCAN_NB 196   // ceil(50000/256)

__global__ void k_hist(const int* __restrict__ rcv, int* __restrict__ cnt){
  int e = blockIdx.x*256 + threadIdx.x;
  if (e < NE) atomicAdd(&cnt[rcv[e]], 1);
}

__global__ void k_scanA(const int* __restrict__ cnt, int* __restrict__ bsum){
  __shared__ int sh[256];
  int i = blockIdx.x*256 + threadIdx.x;
  int v = (i < NN) ? cnt[i] : 0;
  sh[threadIdx.x] = v; __syncthreads();
  for (int off=128; off>0; off>>=1){
    if (threadIdx.x < off) sh[threadIdx.x] += sh[threadIdx.x+off];
    __syncthreads();
  }
  if (threadIdx.x==0) bsum[blockIdx.x] = sh[0];
}

__global__ void k_scanB(int* __restrict__ bsum){
  __shared__ int sh[256];
  int t = threadIdx.x;
  int v = (t < SCAN_NB) ? bsum[t] : 0;
  sh[t] = v; __syncthreads();
  for (int off=1; off<256; off<<=1){
    int x = (t>=off)? sh[t-off] : 0;
    __syncthreads();
    sh[t] += x;
    __syncthreads();
  }
  if (t < SCAN_NB) bsum[t] = sh[t] - v;   // exclusive
}

__global__ void k_scanC(const int* __restrict__ cnt, const int* __restrict__ bsum,
                        int* __restrict__ offs, int* __restrict__ cursor){
  __shared__ int sh[256];
  int t = threadIdx.x;
  int i = blockIdx.x*256 + t;
  int v = (i < NN) ? cnt[i] : 0;
  sh[t] = v; __syncthreads();
  for (int off=1; off<256; off<<=1){
    int x = (t>=off)? sh[t-off] : 0;
    __syncthreads();
    sh[t] += x;
    __syncthreads();
  }
  int excl = sh[t] - v + bsum[blockIdx.x];
  if (i < NN){ offs[i] = excl; cursor[i] = excl; }
}

// store SENDER id directly in CSR order (removes one indirection in k_edge)
__global__ void k_scatter(const int* __restrict__ rcv, const int* __restrict__ snd,
                          int* __restrict__ cursor, int* __restrict__ csr_snd){
  int e = blockIdx.x*256 + threadIdx.x;
  if (e < NE){
    int p = atomicAdd(&cursor[rcv[e]], 1);
    csr_snd[p] = snd[e];
  }
}

// Ge[n][t][l] (float4 per (n,t), l=0..3 -> W0..W3), Gsc[n][t] for self term.
__global__ __launch_bounds__(256) void k_gemm(
    const float* __restrict__ feat,
    const float* __restrict__ W0, const float* __restrict__ W1,
    const float* __restrict__ W2, const float* __restrict__ W3,
    const float* __restrict__ Wsc,
    float4* __restrict__ Ge, float* __restrict__ Gsc)
{
  __shared__ float Wl[5][2048];
  const int tid = threadIdx.x;
  {
    const float* src[5] = {W0,W1,W2,W3,Wsc};
    #pragma unroll
    for (int w=0; w<5; ++w)
      for (int i=tid; i<2048; i+=256)
        Wl[w][i] = src[w][i];
  }
  __syncthreads();
  const int wv = tid>>6, lane = tid&63;
  for (int rep=0; rep<4; ++rep){
    const int n = blockIdx.x*16 + rep*4 + wv;   // 3125*16 == 50000
    const float* fr = feat + (size_t)n*32;
    float a0=0,a1=0,a2=0,a3=0,a4=0;
    #pragma unroll
    for (int m=0; m<32; ++m){
      float f = fr[m];                 // wave-uniform -> scalar load
      a0 += f*Wl[0][m*64+lane];
      a1 += f*Wl[1][m*64+lane];
      a2 += f*Wl[2][m*64+lane];
      a3 += f*Wl[3][m*64+lane];
      a4 += f*Wl[4][m*64+lane];
    }
    Ge[(size_t)n*64 + lane] = make_float4(a0,a1,a2,a3);
    Gsc[(size_t)n*64 + lane] = a4;
  }
}

// One wave per node, lane = output channel t. Edge stage: lane e computes SH
// for edge e into LDS; accumulate stage: coalesced float4 gather of Ge[s][t].
__global__ __launch_bounds__(256) void k_edge(
    const float* __restrict__ pos, const float4* __restrict__ Ge,
    const float* __restrict__ Gsc, const int* __restrict__ offs,
    const int* __restrict__ cnt, const int* __restrict__ csr_snd,
    float* __restrict__ out)
{
  __shared__ __align__(16) float shb[4][64][16];
  __shared__ int slist[4][64];
  __shared__ int smx[4];

  const int tid = threadIdx.x, wv = tid>>6, lane = tid&63;
  const int n = blockIdx.x*4 + wv;          // 12500*4 == 50000
  const float pnx=pos[n*3], pny=pos[n*3+1], pnz=pos[n*3+2];
  const int start = offs[n], deg = cnt[n];
  if (lane==0) smx[wv] = (deg+63)>>6;
  __syncthreads();
  const int mx = max(max(smx[0],smx[1]),max(smx[2],smx[3]));

  float acc[16];
  #pragma unroll
  for (int k=0;k<16;++k) acc[k]=0.f;

  const float SC3=1.7320508f, SC5=2.236068f, SC7=2.6457513f, SC15=3.8729833f,
              SC42=6.4807407f, SC70=8.3666003f, SC105=10.246951f;

  for (int c=0; c<mx; ++c){
    const int base = c<<6;
    int cn = deg - base; cn = (cn>64)?64:cn;     // may be <=0
    if (lane < cn){
      int s = csr_snd[start+base+lane];
      float rx = pnx - pos[s*3];
      float ry = pny - pos[s*3+1];
      float rz = pnz - pos[s*3+2];
      float r = sqrtf(rx*rx+ry*ry+rz*rz);
      float inv = 1.0f/fmaxf(r,1e-12f);
      float x=rx*inv, y=ry*inv, z=rz*inv;
      float x2=x*x, y2=y*y, z2=z*z;
      float s1=SC3*x, s2=SC3*y, s3=SC3*z;
      float s4=SC15*x*y, s5=SC15*y*z, s6=0.5f*SC5*(3.f*z2-1.f), s7=SC15*x*z;
      float s8=0.5f*SC15*(x2-y2);
      float s9 =0.25f*SC70*y*(3.f*x2-y2);
      float s10=SC105*x*y*z;
      float s11=0.25f*SC42*y*(5.f*z2-1.f);
      float s12=0.5f*SC7*z*(5.f*z2-3.f);
      float s13=0.25f*SC42*x*(5.f*z2-1.f);
      float s14=0.5f*SC105*z*(x2-y2);
      float s15=0.25f*SC70*x*(x2-3.f*y2);
      float4* wp = (float4*)&shb[wv][lane][0];
      wp[0] = make_float4(1.0f,s1,s2,s3);
      wp[1] = make_float4(s4,s5,s6,s7);
      wp[2] = make_float4(s8,s9,s10,s11);
      wp[3] = make_float4(s12,s13,s14,s15);
      slist[wv][lane] = s;
    }
    __syncthreads();
    #pragma unroll 4
    for (int it=0; it<cn; ++it){
      int s = __builtin_amdgcn_readfirstlane(slist[wv][it]);
      float4 g = Ge[(size_t)s*64 + lane];
      const float4* rp = (const float4*)&shb[wv][it][0];
      float4 q0=rp[0], q1=rp[1], q2=rp[2], q3=rp[3];
      acc[0] += g.x;                 // sh0 == 1
      acc[1] += g.y*q0.y; acc[2] += g.y*q0.z; acc[3] += g.y*q0.w;
      acc[4] += g.z*q1.x; acc[5] += g.z*q1.y; acc[6] += g.z*q1.z;
      acc[7] += g.z*q1.w; acc[8] += g.z*q2.x;
      acc[9] += g.w*q2.y; acc[10]+= g.w*q2.z; acc[11]+= g.w*q2.w;
      acc[12]+= g.w*q3.x; acc[13]+= g.w*q3.y; acc[14]+= g.w*q3.z; acc[15]+= g.w*q3.w;
    }
    __syncthreads();
  }

  const float S = 0.17677669529663687f;   // 1/sqrt(32)
  const float S8 = S*0.125f;              // edge terms also carry /DENOM
  float gsc = Gsc[(size_t)n*64 + lane];
  float* o = out + (size_t)n*1024;
  o[lane] = acc[0]*S8 + gsc*S;
  #pragma unroll
  for (int i=0;i<3;++i) o[64  + lane*3 + i] = acc[1+i]*S8;
  #pragma unroll
  for (int i=0;i<5;++i) o[256 + lane*5 + i] = acc[4+i]*S8;
  #pragma unroll
  for (int i=0;i<7;++i) o[576 + lane*7 + i] = acc[9+i]*S8;
}

extern "C" void kernel_launch(void* const* d_in, const int* in_sizes, int n_in,
                              void* d_out, int out_size, void* d_ws, size_t ws_size,
                              hipStream_t stream) {
  const float* pos  = (const float*)d_in[0];
  const float* feat = (const float*)d_in[1];
  const float* W0   = (const float*)d_in[2];
  const float* W1   = (const float*)d_in[3];
  const float* W2   = (const float*)d_in[4];
  const float* W3   = (const float*)d_in[5];
  const float* Wsc  = (const float*)d_in[6];
  const int*  snd   = (const int*)d_in[7];
  const int*  rcv   = (const int*)d_in[8];
  float* out = (float*)d_out;

  int* ws      = (int*)d_ws;
  int* cnt     = ws;            // 50000
  int* offs    = ws + 50000;    // 50000
  int* cursor  = ws + 100000;   // 50000
  int* bsum    = ws + 150000;   // 256
  int* csr_snd = ws + 150272;   // 400000  (ends at int 550272)
  float4* Ge   = (float4*)(ws + 550272);          // 50000*64 float4 = 51.2 MB
  float*  Gsc  = (float*)(ws + 550272 + 12800000);// 50000*64 floats = 12.8 MB

  hipMemsetAsync(cnt, 0, NN*sizeof(int), stream);
  k_hist   <<<(NE+255)/256, 256, 0, stream>>>(rcv, cnt);
  k_scanA  <<<SCAN_NB, 256, 0, stream>>>(cnt, bsum);
  k_scanB  <<<1, 256, 0, stream>>>(bsum);
  k_scanC  <<<SCAN_NB, 256, 0, stream>>>(cnt, bsum, offs, cursor);
  k_scatter<<<(NE+255)/256, 256, 0, stream>>>(rcv, snd, cursor, csr_snd);
  k_gemm   <<<3125, 256, 0, stream>>>(feat, W0, W1, W2, W3, Wsc, Ge, Gsc);
  k_edge   <<<12500, 256, 0, stream>>>(pos, Ge, Gsc, offs, cnt, csr_snd, out);
}